// Round 1
// baseline (3076.972 us; speedup 1.0000x reference)
//
#include <hip/hip_runtime.h>
#include <hip/hip_bf16.h>
#include <stdint.h>

#define B_  4096
#define D_  1024
#define NS_ 16000
#define C_  1000
#define H_  256

typedef __attribute__((ext_vector_type(8))) short bf16x8;
typedef __attribute__((ext_vector_type(4))) float f32x4;

__device__ __forceinline__ unsigned short f2bf(float f) {
  union { float f; unsigned u; } v; v.f = f;
  unsigned u = v.u;
  u += 0x7FFF + ((u >> 16) & 1);   // round-to-nearest-even
  return (unsigned short)(u >> 16);
}

// ---------------- fp32 -> bf16 conversion for q, keys, fc1_w ----------------
__global__ void convert_kernel(const float4* __restrict__ q, const float4* __restrict__ keys,
                               const float4* __restrict__ fc1,
                               ushort4* __restrict__ qb, ushort4* __restrict__ keysb,
                               ushort4* __restrict__ fc1b) {
  const size_t nq = (size_t)B_ * D_ / 4;
  const size_t nk = (size_t)NS_ * D_ / 4;
  const size_t nf = (size_t)H_ * D_ / 4;
  const size_t total = nq + nk + nf;
  for (size_t i = blockIdx.x * (size_t)blockDim.x + threadIdx.x; i < total;
       i += (size_t)gridDim.x * blockDim.x) {
    const float4* s; ushort4* d; size_t o;
    if (i < nq)            { s = q;    d = qb;    o = i; }
    else if (i < nq + nk)  { s = keys; d = keysb; o = i - nq; }
    else                   { s = fc1;  d = fc1b;  o = i - nq - nk; }
    float4 v = s[o];
    ushort4 r;
    r.x = f2bf(v.x); r.y = f2bf(v.y); r.z = f2bf(v.z); r.w = f2bf(v.w);
    d[o] = r;
  }
}

// ---------------- extract labels from one-hot values (wave per row) ----------------
__global__ void labels_kernel(const float* __restrict__ values, int* __restrict__ labels) {
  const int s = (int)((blockIdx.x * blockDim.x + threadIdx.x) >> 6);
  const int lane = threadIdx.x & 63;
  if (s >= NS_) return;
  const float* row = values + (size_t)s * C_;
  for (int j = lane; j < C_; j += 64) {
    if (row[j] > 0.5f) labels[s] = j;
  }
}

// ---------------- 128x128 bf16 MFMA GEMM (A row-major [M,K], B row-major [N,K]) ------
// MODE 0: sim epilogue -> aff = exp(beta[row]*sim), atomicAdd into outp[row*C_ + label[col]]
// MODE 1: x epilogue   -> outp[row*H_ + col] = relu(acc + bias[col])
template<int MODE>
__global__ __launch_bounds__(256, 2) void gemm_kernel(
    const short* __restrict__ A, const short* __restrict__ Bm,
    const int* __restrict__ labels, const float* __restrict__ beta,
    const float* __restrict__ bias, float* __restrict__ outp)
{
  __shared__ short As[128 * 64];
  __shared__ short Bs[128 * 64];
  __shared__ float sbeta[128];
  __shared__ int   slab[128];

  const int tid  = threadIdx.x;
  const int wave = tid >> 6, lane = tid & 63;
  const int quad = lane >> 4, l16 = lane & 15;
  const int wm = wave >> 1, wn = wave & 1;     // 2x2 wave grid, 64x64 per wave
  const int rstart = blockIdx.x * 128;
  const int nstart = blockIdx.y * 128;

  if (MODE == 0 && tid < 128) {
    sbeta[tid] = beta[rstart + tid];
    slab[tid]  = labels[nstart + tid];
  }

  f32x4 acc[4][4];
  #pragma unroll
  for (int i = 0; i < 4; ++i)
    #pragma unroll
    for (int j = 0; j < 4; ++j) acc[i][j] = (f32x4)0.f;

  const int r_  = (lane >> 3);      // 0..7
  const int kk_ = (lane & 7) * 8;   // 0..56

  for (int kt = 0; kt < D_; kt += 64) {
    __syncthreads();
    #pragma unroll
    for (int i = 0; i < 4; ++i) {
      const int chunk = i * 4 + wave;       // 0..15, wave-uniform
      const int r = chunk * 8 + r_;         // 0..127
      const short* gA = A  + (size_t)(rstart + r) * D_ + kt + kk_;
      const short* gB = Bm + (size_t)(nstart + r) * D_ + kt + kk_;
      __builtin_amdgcn_global_load_lds(
          (const __attribute__((address_space(1))) void*)gA,
          (__attribute__((address_space(3))) void*)(As + chunk * 512), 16, 0, 0);
      __builtin_amdgcn_global_load_lds(
          (const __attribute__((address_space(1))) void*)gB,
          (__attribute__((address_space(3))) void*)(Bs + chunk * 512), 16, 0, 0);
    }
    __syncthreads();
    #pragma unroll
    for (int ks = 0; ks < 64; ks += 32) {
      bf16x8 af[4], bfr[4];
      #pragma unroll
      for (int mt = 0; mt < 4; ++mt)
        af[mt] = *(const bf16x8*)(As + (wm * 64 + mt * 16 + l16) * 64 + ks + quad * 8);
      #pragma unroll
      for (int nt = 0; nt < 4; ++nt)
        bfr[nt] = *(const bf16x8*)(Bs + (wn * 64 + nt * 16 + l16) * 64 + ks + quad * 8);
      #pragma unroll
      for (int mt = 0; mt < 4; ++mt)
        #pragma unroll
        for (int nt = 0; nt < 4; ++nt)
          acc[mt][nt] = __builtin_amdgcn_mfma_f32_16x16x32_bf16(af[mt], bfr[nt], acc[mt][nt], 0, 0, 0);
    }
  }

  if (MODE == 0) {
    #pragma unroll
    for (int mt = 0; mt < 4; ++mt) {
      const int rbase = wm * 64 + mt * 16 + quad * 4;
      #pragma unroll
      for (int nt = 0; nt < 4; ++nt) {
        const int cc = wn * 64 + nt * 16 + l16;
        const int lab = slab[cc];
        #pragma unroll
        for (int r = 0; r < 4; ++r) {
          const int row = rbase + r;
          float aff = __expf(sbeta[row] * acc[mt][nt][r]);
          atomicAdd(outp + (size_t)(rstart + row) * C_ + lab, aff);
        }
      }
    }
  } else {
    #pragma unroll
    for (int mt = 0; mt < 4; ++mt) {
      const int rbase = wm * 64 + mt * 16 + quad * 4;
      #pragma unroll
      for (int nt = 0; nt < 4; ++nt) {
        const int cc = nstart + wn * 64 + nt * 16 + l16;
        const float bv = bias[cc];
        #pragma unroll
        for (int r = 0; r < 4; ++r) {
          float v = acc[mt][nt][r] + bv;
          outp[(size_t)(rstart + rbase + r) * H_ + cc] = v > 0.f ? v : 0.f;
        }
      }
    }
  }
}

// ---------------- gate: g = x @ fc2^T + b; alpha = sigmoid, beta = softplus + 1e-3 ----
__global__ void gate_kernel(const float* __restrict__ x, const float* __restrict__ fc2_w,
                            const float* __restrict__ fc2_b, float* __restrict__ ab) {
  const int w = (int)((blockIdx.x * blockDim.x + threadIdx.x) >> 6);
  const int lane = threadIdx.x & 63;
  if (w >= B_) return;
  const float* xr = x + (size_t)w * H_;
  float g0 = 0.f, g1 = 0.f;
  #pragma unroll
  for (int j = 0; j < H_; j += 64) {
    float v = xr[j + lane];
    g0 += v * fc2_w[j + lane];
    g1 += v * fc2_w[H_ + j + lane];
  }
  #pragma unroll
  for (int off = 32; off > 0; off >>= 1) {
    g0 += __shfl_down(g0, off);
    g1 += __shfl_down(g1, off);
  }
  if (lane == 0) {
    g0 += fc2_b[0];
    g1 += fc2_b[1];
    ab[w]      = 1.f / (1.f + __expf(-g0));                                  // alpha
    ab[B_ + w] = fmaxf(g1, 0.f) + log1pf(__expf(-fabsf(g1))) + 0.001f;       // beta
  }
}

// ---------------- fusion: out = ((1-a)*z + a*c) * post_scale (in-place over c) -------
__global__ void fuse_kernel(float* __restrict__ out, const float* __restrict__ z,
                            const float* __restrict__ ps) {
  const int b = blockIdx.x;
  const int t = threadIdx.x;
  const float a = out[(size_t)B_ * C_ + b];
  const float scale = ps[0];
  float4* o4 = (float4*)(out + (size_t)b * C_);
  const float4* z4 = (const float4*)(z + (size_t)b * C_);
  if (t < C_ / 4) {
    float4 c = o4[t];
    float4 zz = z4[t];
    float4 r;
    r.x = ((1.f - a) * zz.x + a * c.x) * scale;
    r.y = ((1.f - a) * zz.y + a * c.y) * scale;
    r.z = ((1.f - a) * zz.z + a * c.z) * scale;
    r.w = ((1.f - a) * zz.w + a * c.w) * scale;
    o4[t] = r;
  }
}

extern "C" void kernel_launch(void* const* d_in, const int* in_sizes, int n_in,
                              void* d_out, int out_size, void* d_ws, size_t ws_size,
                              hipStream_t stream) {
  const float* q          = (const float*)d_in[0];
  const float* z          = (const float*)d_in[1];
  const float* keys       = (const float*)d_in[2];
  const float* values     = (const float*)d_in[3];
  const float* fc1_w      = (const float*)d_in[4];
  const float* fc1_b      = (const float*)d_in[5];
  const float* fc2_w      = (const float*)d_in[6];
  const float* fc2_b      = (const float*)d_in[7];
  const float* post_scale = (const float*)d_in[8];
  float* out = (float*)d_out;

  // ws layout (all 16B-aligned): qb 8MB | keysb 32MB | fc1b 512KB | labels 64KB | x 4MB
  char* ws = (char*)d_ws;
  short* qb     = (short*)(ws);
  short* keysb  = (short*)(ws + 8388608);
  short* fc1b   = (short*)(ws + 41156608);
  int*   labels = (int*)  (ws + 41680896);
  float* x      = (float*)(ws + 41744896);

  float* alpha = out + (size_t)B_ * C_;   // alpha/beta written directly to output tail

  convert_kernel<<<2048, 256, 0, stream>>>(
      (const float4*)q, (const float4*)keys, (const float4*)fc1_w,
      (ushort4*)qb, (ushort4*)keysb, (ushort4*)fc1b);

  labels_kernel<<<(NS_ * 64) / 256, 256, 0, stream>>>(values, labels);

  hipMemsetAsync(d_out, 0, (size_t)B_ * C_ * sizeof(float), stream);  // zero c accumulator

  gemm_kernel<1><<<dim3(B_ / 128, H_ / 128), 256, 0, stream>>>(
      qb, fc1b, nullptr, nullptr, fc1_b, x);

  gate_kernel<<<(B_ * 64) / 256, 256, 0, stream>>>(x, fc2_w, fc2_b, alpha);

  gemm_kernel<0><<<dim3(B_ / 128, NS_ / 128), 256, 0, stream>>>(
      qb, keysb, labels, alpha + B_, nullptr, out);

  fuse_kernel<<<B_, 256, 0, stream>>>(out, z, post_scale);
}

// Round 2
// 480.817 us; speedup vs baseline: 6.3995x; 6.3995x over previous
//
#include <hip/hip_runtime.h>
#include <hip/hip_bf16.h>
#include <stdint.h>

#define B_  4096
#define D_  1024
#define NS_ 16000
#define C_  1000
#define H_  256

typedef __attribute__((ext_vector_type(8))) short bf16x8;
typedef __attribute__((ext_vector_type(4))) float f32x4;

__device__ __forceinline__ unsigned short f2bf(float f) {
  union { float f; unsigned u; } v; v.f = f;
  unsigned u = v.u;
  u += 0x7FFF + ((u >> 16) & 1);   // round-to-nearest-even
  return (unsigned short)(u >> 16);
}

// ---------------- fp32 -> bf16 convert; keys rows permuted by posmap ----------------
__global__ void convert_kernel(const float4* __restrict__ q, const float4* __restrict__ keys,
                               const float4* __restrict__ fc1, const int* __restrict__ posmap,
                               ushort4* __restrict__ qb, ushort4* __restrict__ keysb,
                               ushort4* __restrict__ fc1b) {
  const size_t nq = (size_t)B_ * D_ / 4;
  const size_t nk = (size_t)NS_ * D_ / 4;
  const size_t nf = (size_t)H_ * D_ / 4;
  const size_t total = nq + nk + nf;
  for (size_t i = blockIdx.x * (size_t)blockDim.x + threadIdx.x; i < total;
       i += (size_t)gridDim.x * blockDim.x) {
    if (i < nq) {
      float4 v = q[i];
      ushort4 r; r.x = f2bf(v.x); r.y = f2bf(v.y); r.z = f2bf(v.z); r.w = f2bf(v.w);
      qb[i] = r;
    } else if (i < nq + nk) {
      size_t o = i - nq;
      size_t row = o >> 8;           // D_/4 = 256 float4 per row
      size_t c4  = o & 255;
      float4 v = keys[o];
      ushort4 r; r.x = f2bf(v.x); r.y = f2bf(v.y); r.z = f2bf(v.z); r.w = f2bf(v.w);
      keysb[(size_t)posmap[row] * 256 + c4] = r;
    } else {
      size_t o = i - nq - nk;
      float4 v = fc1[o];
      ushort4 r; r.x = f2bf(v.x); r.y = f2bf(v.y); r.z = f2bf(v.z); r.w = f2bf(v.w);
      fc1b[o] = r;
    }
  }
}

// ---------------- labels from one-hot + histogram (wave per support row) ------------
__global__ void labels_kernel(const float* __restrict__ values, int* __restrict__ labels,
                              int* __restrict__ hist) {
  const int s = (int)((blockIdx.x * blockDim.x + threadIdx.x) >> 6);
  const int lane = threadIdx.x & 63;
  if (s >= NS_) return;
  const float* row = values + (size_t)s * C_;
  for (int j = lane; j < C_; j += 64) {
    if (row[j] > 0.5f) { labels[s] = j; atomicAdd(&hist[j], 1); }
  }
}

// ---------------- exclusive prefix scan of hist -> boff[0..C_] (single block) -------
__global__ void scan_kernel(const int* __restrict__ hist, int* __restrict__ boff) {
  __shared__ int s[1024];
  const int t = threadIdx.x;
  int v = (t < C_) ? hist[t] : 0;
  s[t] = v; __syncthreads();
  for (int off = 1; off < 1024; off <<= 1) {
    int u = (t >= off) ? s[t - off] : 0;
    __syncthreads();
    s[t] += u;
    __syncthreads();
  }
  if (t == 0) boff[0] = 0;
  if (t < C_) boff[t + 1] = s[t];
}

// ---------------- scatter: sorted position for each support ------------------------
__global__ void scatter_kernel(const int* __restrict__ labels, const int* __restrict__ boff,
                               int* __restrict__ cnt, int* __restrict__ posmap) {
  const int sidx = blockIdx.x * blockDim.x + threadIdx.x;
  if (sidx >= NS_) return;
  const int lab = labels[sidx];
  const int pos = boff[lab] + atomicAdd(&cnt[lab], 1);
  posmap[sidx] = pos;
}

// ---------------- 128x128 bf16 MFMA GEMM (A [M,K], B [N,K], both row-major) ---------
// MODE 0: aff epilogue -> affbuf[row*affStride + col] = bf16(exp(beta[row]*acc))
// MODE 1: x epilogue   -> outp[row*H_ + col] = relu(acc + bias[col])
// LDS k-chunk XOR swizzle: LDS[r][c] holds global 16B k-chunk (c ^ (r&7)).
template<int MODE>
__global__ __launch_bounds__(256, 2) void gemm_kernel(
    const short* __restrict__ A, const short* __restrict__ Bm,
    const float* __restrict__ beta, const float* __restrict__ bias,
    float* __restrict__ outp, unsigned short* __restrict__ affbuf, long affStride)
{
  __shared__ short As[128 * 64];
  __shared__ short Bs[128 * 64];
  __shared__ float sbeta[128];

  const int tid  = threadIdx.x;
  const int wave = tid >> 6, lane = tid & 63;
  const int quad = lane >> 4, l16 = lane & 15;
  const int wm = wave >> 1, wn = wave & 1;     // 2x2 wave grid, 64x64 per wave
  const int rstart = blockIdx.x * 128;
  const int nstart = blockIdx.y * 128;

  if (MODE == 0 && tid < 128) sbeta[tid] = beta[rstart + tid];

  f32x4 acc[4][4];
  #pragma unroll
  for (int i = 0; i < 4; ++i)
    #pragma unroll
    for (int j = 0; j < 4; ++j) acc[i][j] = (f32x4)0.f;

  const int r_  = (lane >> 3);             // 0..7 (row within 8-row chunk)
  const int kc_ = ((lane & 7) ^ r_) * 8;   // swizzled 16B k-chunk element offset

  for (int kt = 0; kt < D_; kt += 64) {
    __syncthreads();
    #pragma unroll
    for (int i = 0; i < 4; ++i) {
      const int chunk = i * 4 + wave;       // 0..15, wave-uniform
      const int r = chunk * 8 + r_;         // 0..127
      const short* gA = A  + (size_t)(rstart + r) * D_ + kt + kc_;
      const short* gB = Bm + (size_t)(nstart + r) * D_ + kt + kc_;
      __builtin_amdgcn_global_load_lds(
          (const __attribute__((address_space(1))) void*)gA,
          (__attribute__((address_space(3))) void*)(As + chunk * 512), 16, 0, 0);
      __builtin_amdgcn_global_load_lds(
          (const __attribute__((address_space(1))) void*)gB,
          (__attribute__((address_space(3))) void*)(Bs + chunk * 512), 16, 0, 0);
    }
    __syncthreads();
    #pragma unroll
    for (int ks = 0; ks < 64; ks += 32) {
      bf16x8 af[4], bfr[4];
      const int kb = (ks >> 3) + quad;      // global k-chunk index 0..7
      #pragma unroll
      for (int mt = 0; mt < 4; ++mt) {
        const int row = wm * 64 + mt * 16 + l16;
        af[mt] = *(const bf16x8*)(As + row * 64 + ((kb ^ (row & 7)) << 3));
      }
      #pragma unroll
      for (int nt = 0; nt < 4; ++nt) {
        const int row = wn * 64 + nt * 16 + l16;
        bfr[nt] = *(const bf16x8*)(Bs + row * 64 + ((kb ^ (row & 7)) << 3));
      }
      #pragma unroll
      for (int mt = 0; mt < 4; ++mt)
        #pragma unroll
        for (int nt = 0; nt < 4; ++nt)
          acc[mt][nt] = __builtin_amdgcn_mfma_f32_16x16x32_bf16(af[mt], bfr[nt], acc[mt][nt], 0, 0, 0);
    }
  }

  if (MODE == 0) {
    #pragma unroll
    for (int mt = 0; mt < 4; ++mt) {
      const int rbase = wm * 64 + mt * 16 + quad * 4;
      #pragma unroll
      for (int nt = 0; nt < 4; ++nt) {
        const long col = nstart + wn * 64 + nt * 16 + l16;
        #pragma unroll
        for (int r = 0; r < 4; ++r) {
          const int row = rbase + r;
          const float v = __expf(sbeta[row] * acc[mt][nt][r]);
          affbuf[(size_t)(rstart + row) * affStride + col] = f2bf(v);
        }
      }
    }
  } else {
    #pragma unroll
    for (int mt = 0; mt < 4; ++mt) {
      const int rbase = wm * 64 + mt * 16 + quad * 4;
      #pragma unroll
      for (int nt = 0; nt < 4; ++nt) {
        const int cc = nstart + wn * 64 + nt * 16 + l16;
        const float bv = bias[cc];
        #pragma unroll
        for (int r = 0; r < 4; ++r) {
          float v = acc[mt][nt][r] + bv;
          outp[(size_t)(rstart + rbase + r) * H_ + cc] = v > 0.f ? v : 0.f;
        }
      }
    }
  }
}

// ---------------- gate: g = x @ fc2^T + b; alpha = sigmoid, beta = softplus + 1e-3 --
__global__ void gate_kernel(const float* __restrict__ x, const float* __restrict__ fc2_w,
                            const float* __restrict__ fc2_b, float* __restrict__ ab) {
  const int w = (int)((blockIdx.x * blockDim.x + threadIdx.x) >> 6);
  const int lane = threadIdx.x & 63;
  if (w >= B_) return;
  const float* xr = x + (size_t)w * H_;
  float g0 = 0.f, g1 = 0.f;
  #pragma unroll
  for (int j = 0; j < H_; j += 64) {
    float v = xr[j + lane];
    g0 += v * fc2_w[j + lane];
    g1 += v * fc2_w[H_ + j + lane];
  }
  #pragma unroll
  for (int off = 32; off > 0; off >>= 1) {
    g0 += __shfl_down(g0, off);
    g1 += __shfl_down(g1, off);
  }
  if (lane == 0) {
    g0 += fc2_b[0];
    g1 += fc2_b[1];
    ab[w]      = 1.f / (1.f + __expf(-g0));                                  // alpha
    ab[B_ + w] = fmaxf(g1, 0.f) + log1pf(__expf(-fabsf(g1))) + 0.001f;       // beta
  }
}

// ---------------- segmented sum over label buckets (+fused epilogue on last chunk) --
// out[b*C + lab] accumulates c; on final chunk: out = ((1-a)*z + a*c) * ps
__global__ void segsum_kernel(const unsigned short* __restrict__ aff,
                              const int* __restrict__ boff,
                              float* __restrict__ out, const float* __restrict__ z,
                              const float* __restrict__ ps,
                              int n0, int n1, long affStride, int final) {
  const int b = blockIdx.x;
  const int t = threadIdx.x;
  const unsigned short* arow = aff + (size_t)b * affStride;
  float a = 0.f, sc = 1.f;
  if (final) { a = out[(size_t)B_ * C_ + b]; sc = ps[0]; }
  for (int lab = t; lab < C_; lab += 256) {
    int s0 = boff[lab], s1 = boff[lab + 1];
    if (s0 < n0) s0 = n0;
    if (s1 > n1) s1 = n1;
    float sum = 0.f;
    for (int s = s0; s < s1; ++s) {
      union { unsigned u; float f; } cv;
      cv.u = ((unsigned)arow[s - n0]) << 16;
      sum += cv.f;
    }
    const size_t oi = (size_t)b * C_ + lab;
    float c = out[oi] + sum;
    out[oi] = final ? ((1.f - a) * z[oi] + a * c) * sc : c;
  }
}

extern "C" void kernel_launch(void* const* d_in, const int* in_sizes, int n_in,
                              void* d_out, int out_size, void* d_ws, size_t ws_size,
                              hipStream_t stream) {
  const float* q          = (const float*)d_in[0];
  const float* z          = (const float*)d_in[1];
  const float* keys       = (const float*)d_in[2];
  const float* values     = (const float*)d_in[3];
  const float* fc1_w      = (const float*)d_in[4];
  const float* fc1_b      = (const float*)d_in[5];
  const float* fc2_w      = (const float*)d_in[6];
  const float* fc2_b      = (const float*)d_in[7];
  const float* post_scale = (const float*)d_in[8];
  float* out = (float*)d_out;

  // ws layout (byte offsets)
  char* ws = (char*)d_ws;
  short*          qb     = (short*)(ws);                       //  8,388,608
  short*          keysb  = (short*)(ws + 8388608);             // 32,768,000
  short*          fc1b   = (short*)(ws + 41156608);            //    524,288
  int*            labels = (int*)  (ws + 41680896);            //     64,000
  float*          x      = (float*)(ws + 41744896);            //  4,194,304
  int*            hist   = (int*)  (ws + 45939200);            //      4,096
  int*            cnt    = (int*)  (ws + 45943296);            //      4,096
  int*            boff   = (int*)  (ws + 45947392);            //      4,096
  int*            posmap = (int*)  (ws + 45951488);            //     64,000
  unsigned short* aff    = (unsigned short*)(ws + 46015488);   //  remainder

  float* alpha = out + (size_t)B_ * C_;   // alpha/beta written directly to output tail
  float* beta  = alpha + B_;

  // chunking of the aff buffer by available workspace (deterministic per call)
  long avail = (long)ws_size - 46015488L;
  long maxN = (avail / (B_ * 2)) & ~127L;       // columns per chunk, multiple of 128
  if (maxN > NS_) maxN = NS_;
  if (maxN < 128) maxN = 128;

  hipMemsetAsync(d_out, 0, (size_t)B_ * C_ * sizeof(float), stream);  // c accumulator
  hipMemsetAsync(hist, 0, 8192, stream);                              // hist + cnt

  labels_kernel<<<(NS_ * 64) / 256, 256, 0, stream>>>(values, labels, hist);
  scan_kernel<<<1, 1024, 0, stream>>>(hist, boff);
  scatter_kernel<<<(NS_ + 255) / 256, 256, 0, stream>>>(labels, boff, cnt, posmap);

  convert_kernel<<<2048, 256, 0, stream>>>(
      (const float4*)q, (const float4*)keys, (const float4*)fc1_w, posmap,
      (ushort4*)qb, (ushort4*)keysb, (ushort4*)fc1b);

  gemm_kernel<1><<<dim3(B_ / 128, H_ / 128), 256, 0, stream>>>(
      qb, fc1b, nullptr, fc1_b, x, nullptr, 0);

  gate_kernel<<<(B_ * 64) / 256, 256, 0, stream>>>(x, fc2_w, fc2_b, alpha);

  for (long n0 = 0; n0 < NS_; n0 += maxN) {
    long nc = NS_ - n0; if (nc > maxN) nc = maxN;
    gemm_kernel<0><<<dim3(B_ / 128, (int)(nc / 128)), 256, 0, stream>>>(
        qb, keysb + n0 * D_, beta, nullptr, nullptr, aff, maxN);
    int final = (n0 + nc >= NS_) ? 1 : 0;
    segsum_kernel<<<B_, 256, 0, stream>>>(aff, boff, out, z, post_scale,
                                          (int)n0, (int)(n0 + nc), maxN, final);
  }
}

// Round 3
// 397.201 us; speedup vs baseline: 7.7466x; 1.2105x over previous
//
#include <hip/hip_runtime.h>
#include <hip/hip_bf16.h>
#include <stdint.h>

#define B_  4096
#define D_  1024
#define NS_ 16000
#define C_  1000
#define H_  256

typedef __attribute__((ext_vector_type(8))) short bf16x8;
typedef __attribute__((ext_vector_type(4))) float f32x4;

__device__ __forceinline__ unsigned short f2bf(float f) {
  union { float f; unsigned u; } v; v.f = f;
  unsigned u = v.u;
  u += 0x7FFF + ((u >> 16) & 1);   // round-to-nearest-even
  return (unsigned short)(u >> 16);
}

__device__ __forceinline__ float bf2f(unsigned short h) {
  union { unsigned u; float f; } v; v.u = ((unsigned)h) << 16;
  return v.f;
}

// ---------------- fp32 -> bf16 convert; keys rows permuted by posmap ----------------
__global__ void convert_kernel(const float4* __restrict__ q, const float4* __restrict__ keys,
                               const float4* __restrict__ fc1, const int* __restrict__ posmap,
                               ushort4* __restrict__ qb, ushort4* __restrict__ keysb,
                               ushort4* __restrict__ fc1b) {
  const size_t nq = (size_t)B_ * D_ / 4;
  const size_t nk = (size_t)NS_ * D_ / 4;
  const size_t nf = (size_t)H_ * D_ / 4;
  const size_t total = nq + nk + nf;
  for (size_t i = blockIdx.x * (size_t)blockDim.x + threadIdx.x; i < total;
       i += (size_t)gridDim.x * blockDim.x) {
    if (i < nq) {
      float4 v = q[i];
      ushort4 r; r.x = f2bf(v.x); r.y = f2bf(v.y); r.z = f2bf(v.z); r.w = f2bf(v.w);
      qb[i] = r;
    } else if (i < nq + nk) {
      size_t o = i - nq;
      size_t row = o >> 8;           // D_/4 = 256 float4 per row
      size_t c4  = o & 255;
      float4 v = keys[o];
      ushort4 r; r.x = f2bf(v.x); r.y = f2bf(v.y); r.z = f2bf(v.z); r.w = f2bf(v.w);
      keysb[(size_t)posmap[row] * 256 + c4] = r;
    } else {
      size_t o = i - nq - nk;
      float4 v = fc1[o];
      ushort4 r; r.x = f2bf(v.x); r.y = f2bf(v.y); r.z = f2bf(v.z); r.w = f2bf(v.w);
      fc1b[o] = r;
    }
  }
}

// ---------------- labels from one-hot + histogram (wave per support row) ------------
__global__ void labels_kernel(const float* __restrict__ values, int* __restrict__ labels,
                              int* __restrict__ hist) {
  const int s = (int)((blockIdx.x * blockDim.x + threadIdx.x) >> 6);
  const int lane = threadIdx.x & 63;
  if (s >= NS_) return;
  const float4* row = (const float4*)(values + (size_t)s * C_);
  for (int j = lane; j < C_ / 4; j += 64) {
    float4 v = row[j];
    int lab = -1;
    if (v.x > 0.5f) lab = j * 4 + 0;
    if (v.y > 0.5f) lab = j * 4 + 1;
    if (v.z > 0.5f) lab = j * 4 + 2;
    if (v.w > 0.5f) lab = j * 4 + 3;
    if (lab >= 0) { labels[s] = lab; atomicAdd(&hist[lab], 1); }
  }
}

// ---------------- exclusive prefix scan of hist -> boff[0..C_] (single block) -------
__global__ void scan_kernel(const int* __restrict__ hist, int* __restrict__ boff) {
  __shared__ int s[1024];
  const int t = threadIdx.x;
  int v = (t < C_) ? hist[t] : 0;
  s[t] = v; __syncthreads();
  for (int off = 1; off < 1024; off <<= 1) {
    int u = (t >= off) ? s[t - off] : 0;
    __syncthreads();
    s[t] += u;
    __syncthreads();
  }
  if (t == 0) boff[0] = 0;
  if (t < C_) boff[t + 1] = s[t];
}

// ---------------- scatter: sorted position for each support ------------------------
__global__ void scatter_kernel(const int* __restrict__ labels, const int* __restrict__ boff,
                               int* __restrict__ cnt, int* __restrict__ posmap) {
  const int sidx = blockIdx.x * blockDim.x + threadIdx.x;
  if (sidx >= NS_) return;
  const int lab = labels[sidx];
  const int pos = boff[lab] + atomicAdd(&cnt[lab], 1);
  posmap[sidx] = pos;
}

// ---------------- 128x128 bf16 MFMA GEMM (A [M,K], B [N,K], both row-major) ---------
// MODE 0: aff epilogue -> affbuf[row*affStride + col] = bf16(exp(beta[row]*acc))
// MODE 1: x epilogue   -> outp[row*H_ + col] = relu(acc + bias[col])
// LDS k-chunk XOR swizzle: LDS[r][c] holds global 16B k-chunk (c ^ (r&7)).
template<int MODE>
__global__ __launch_bounds__(256, 2) void gemm_kernel(
    const short* __restrict__ A, const short* __restrict__ Bm,
    const float* __restrict__ beta, const float* __restrict__ bias,
    float* __restrict__ outp, unsigned short* __restrict__ affbuf, long affStride)
{
  __shared__ short As[128 * 64];
  __shared__ short Bs[128 * 64];
  __shared__ float sbeta[128];

  const int tid  = threadIdx.x;
  const int wave = tid >> 6, lane = tid & 63;
  const int quad = lane >> 4, l16 = lane & 15;
  const int wm = wave >> 1, wn = wave & 1;     // 2x2 wave grid, 64x64 per wave
  const int rstart = blockIdx.x * 128;
  const int nstart = blockIdx.y * 128;

  if (MODE == 0 && tid < 128) sbeta[tid] = beta[rstart + tid];

  f32x4 acc[4][4];
  #pragma unroll
  for (int i = 0; i < 4; ++i)
    #pragma unroll
    for (int j = 0; j < 4; ++j) acc[i][j] = (f32x4)0.f;

  const int r_  = (lane >> 3);             // 0..7 (row within 8-row chunk)
  const int kc_ = ((lane & 7) ^ r_) * 8;   // swizzled 16B k-chunk element offset

  for (int kt = 0; kt < D_; kt += 64) {
    __syncthreads();
    #pragma unroll
    for (int i = 0; i < 4; ++i) {
      const int chunk = i * 4 + wave;       // 0..15, wave-uniform
      const int r = chunk * 8 + r_;         // 0..127
      const short* gA = A  + (size_t)(rstart + r) * D_ + kt + kc_;
      const short* gB = Bm + (size_t)(nstart + r) * D_ + kt + kc_;
      __builtin_amdgcn_global_load_lds(
          (const __attribute__((address_space(1))) void*)gA,
          (__attribute__((address_space(3))) void*)(As + chunk * 512), 16, 0, 0);
      __builtin_amdgcn_global_load_lds(
          (const __attribute__((address_space(1))) void*)gB,
          (__attribute__((address_space(3))) void*)(Bs + chunk * 512), 16, 0, 0);
    }
    __syncthreads();
    #pragma unroll
    for (int ks = 0; ks < 64; ks += 32) {
      bf16x8 af[4], bfr[4];
      const int kb = (ks >> 3) + quad;      // global k-chunk index 0..7
      #pragma unroll
      for (int mt = 0; mt < 4; ++mt) {
        const int row = wm * 64 + mt * 16 + l16;
        af[mt] = *(const bf16x8*)(As + row * 64 + ((kb ^ (row & 7)) << 3));
      }
      #pragma unroll
      for (int nt = 0; nt < 4; ++nt) {
        const int row = wn * 64 + nt * 16 + l16;
        bfr[nt] = *(const bf16x8*)(Bs + row * 64 + ((kb ^ (row & 7)) << 3));
      }
      #pragma unroll
      for (int mt = 0; mt < 4; ++mt)
        #pragma unroll
        for (int nt = 0; nt < 4; ++nt)
          acc[mt][nt] = __builtin_amdgcn_mfma_f32_16x16x32_bf16(af[mt], bfr[nt], acc[mt][nt], 0, 0, 0);
    }
  }

  if (MODE == 0) {
    #pragma unroll
    for (int mt = 0; mt < 4; ++mt) {
      const int rbase = wm * 64 + mt * 16 + quad * 4;
      #pragma unroll
      for (int nt = 0; nt < 4; ++nt) {
        const long col = nstart + wn * 64 + nt * 16 + l16;
        #pragma unroll
        for (int r = 0; r < 4; ++r) {
          const int row = rbase + r;
          const float v = __expf(sbeta[row] * acc[mt][nt][r]);
          affbuf[(size_t)(rstart + row) * affStride + col] = f2bf(v);
        }
      }
    }
  } else {
    #pragma unroll
    for (int mt = 0; mt < 4; ++mt) {
      const int rbase = wm * 64 + mt * 16 + quad * 4;
      #pragma unroll
      for (int nt = 0; nt < 4; ++nt) {
        const int cc = nstart + wn * 64 + nt * 16 + l16;
        const float bv = bias[cc];
        #pragma unroll
        for (int r = 0; r < 4; ++r) {
          float v = acc[mt][nt][r] + bv;
          outp[(size_t)(rstart + rbase + r) * H_ + cc] = v > 0.f ? v : 0.f;
        }
      }
    }
  }
}

// ---------------- gate: g = x @ fc2^T + b; alpha = sigmoid, beta = softplus + 1e-3 --
__global__ void gate_kernel(const float* __restrict__ x, const float* __restrict__ fc2_w,
                            const float* __restrict__ fc2_b, float* __restrict__ ab) {
  const int w = (int)((blockIdx.x * blockDim.x + threadIdx.x) >> 6);
  const int lane = threadIdx.x & 63;
  if (w >= B_) return;
  const float* xr = x + (size_t)w * H_;
  float g0 = 0.f, g1 = 0.f;
  #pragma unroll
  for (int j = 0; j < H_; j += 64) {
    float v = xr[j + lane];
    g0 += v * fc2_w[j + lane];
    g1 += v * fc2_w[H_ + j + lane];
  }
  #pragma unroll
  for (int off = 32; off > 0; off >>= 1) {
    g0 += __shfl_down(g0, off);
    g1 += __shfl_down(g1, off);
  }
  if (lane == 0) {
    g0 += fc2_b[0];
    g1 += fc2_b[1];
    ab[w]      = 1.f / (1.f + __expf(-g0));                                  // alpha
    ab[B_ + w] = fmaxf(g1, 0.f) + log1pf(__expf(-fabsf(g1))) + 0.001f;       // beta
  }
}

// ---------------- segmented sum over label buckets, LDS-staged ----------------------
// Stages the aff row (<=16384 bf16) + boff into LDS with coalesced int4 loads, then
// each thread sums its label buckets from LDS.
// flags bit0 = first chunk (write, don't read out); bit1 = final chunk (apply fusion).
__global__ __launch_bounds__(256) void segsum_kernel(
    const unsigned short* __restrict__ aff, const int* __restrict__ boff,
    float* __restrict__ out, const float* __restrict__ z, const float* __restrict__ ps,
    int n0, int n1, long affStride, int flags) {
  __shared__ unsigned short srow[16384];
  __shared__ int sboff[C_ + 1];
  const int b = blockIdx.x;
  const int t = threadIdx.x;
  const int nc = n1 - n0;                      // multiple of 128
  const int4* src = (const int4*)(aff + (size_t)b * affStride);
  int4* dst = (int4*)srow;
  for (int i = t; i < nc / 8; i += 256) dst[i] = src[i];
  for (int i = t; i <= C_; i += 256) sboff[i] = boff[i];
  __syncthreads();
  float a = 0.f, sc = 1.f;
  if (flags & 2) { a = out[(size_t)B_ * C_ + b]; sc = ps[0]; }
  for (int lab = t; lab < C_; lab += 256) {
    int s0 = sboff[lab], s1 = sboff[lab + 1];
    if (s0 < n0) s0 = n0;
    if (s1 > n1) s1 = n1;
    float sum = 0.f;
    for (int s = s0; s < s1; ++s) sum += bf2f(srow[s - n0]);
    const size_t oi = (size_t)b * C_ + lab;
    float c = (flags & 1) ? sum : out[oi] + sum;
    out[oi] = (flags & 2) ? ((1.f - a) * z[oi] + a * c) * sc : c;
  }
}

extern "C" void kernel_launch(void* const* d_in, const int* in_sizes, int n_in,
                              void* d_out, int out_size, void* d_ws, size_t ws_size,
                              hipStream_t stream) {
  const float* q          = (const float*)d_in[0];
  const float* z          = (const float*)d_in[1];
  const float* keys       = (const float*)d_in[2];
  const float* values     = (const float*)d_in[3];
  const float* fc1_w      = (const float*)d_in[4];
  const float* fc1_b      = (const float*)d_in[5];
  const float* fc2_w      = (const float*)d_in[6];
  const float* fc2_b      = (const float*)d_in[7];
  const float* post_scale = (const float*)d_in[8];
  float* out = (float*)d_out;

  // ws layout (byte offsets)
  char* ws = (char*)d_ws;
  short*          qb     = (short*)(ws);                       //  8,388,608
  short*          keysb  = (short*)(ws + 8388608);             // 32,768,000
  short*          fc1b   = (short*)(ws + 41156608);            //    524,288
  int*            labels = (int*)  (ws + 41680896);            //     64,000
  float*          x      = (float*)(ws + 41744896);            //  4,194,304
  int*            hist   = (int*)  (ws + 45939200);            //      4,096
  int*            cnt    = (int*)  (ws + 45943296);            //      4,096
  int*            boff   = (int*)  (ws + 45947392);            //      4,096
  int*            posmap = (int*)  (ws + 45951488);            //     64,000
  unsigned short* aff    = (unsigned short*)(ws + 46015488);   //  remainder

  float* alpha = out + (size_t)B_ * C_;   // alpha/beta written directly to output tail
  float* beta  = alpha + B_;

  // chunking of the aff buffer by available workspace (deterministic per call)
  long avail = (long)ws_size - 46015488L;
  long maxN = (avail / (B_ * 2)) & ~127L;       // columns per chunk, multiple of 128
  if (maxN > NS_) maxN = NS_;
  if (maxN > 16384) maxN = 16384;               // segsum LDS staging capacity
  if (maxN < 128) maxN = 128;

  hipMemsetAsync(hist, 0, 8192, stream);                              // hist + cnt

  labels_kernel<<<(NS_ * 64) / 256, 256, 0, stream>>>(values, labels, hist);
  scan_kernel<<<1, 1024, 0, stream>>>(hist, boff);
  scatter_kernel<<<(NS_ + 255) / 256, 256, 0, stream>>>(labels, boff, cnt, posmap);

  convert_kernel<<<2048, 256, 0, stream>>>(
      (const float4*)q, (const float4*)keys, (const float4*)fc1_w, posmap,
      (ushort4*)qb, (ushort4*)keysb, (ushort4*)fc1b);

  gemm_kernel<1><<<dim3(B_ / 128, H_ / 128), 256, 0, stream>>>(
      qb, fc1b, nullptr, fc1_b, x, nullptr, 0);

  gate_kernel<<<(B_ * 64) / 256, 256, 0, stream>>>(x, fc2_w, fc2_b, alpha);

  for (long n0 = 0; n0 < NS_; n0 += maxN) {
    long nc = NS_ - n0; if (nc > maxN) nc = maxN;
    gemm_kernel<0><<<dim3(B_ / 128, (int)(nc / 128)), 256, 0, stream>>>(
        qb, keysb + n0 * D_, beta, nullptr, nullptr, aff, maxN);
    int flags = (n0 == 0 ? 1 : 0) | ((n0 + nc >= NS_) ? 2 : 0);
    segsum_kernel<<<B_, 256, 0, stream>>>(aff, boff, out, z, post_scale,
                                          (int)n0, (int)(n0 + nc), maxN, flags);
  }
}